// Round 8
// baseline (175.552 us; speedup 1.0000x reference)
//
#include <hip/hip_runtime.h>
#include <hip/hip_cooperative_groups.h>
#include <cstdint>
#include <math.h>

namespace cg = cooperative_groups;

#define B_SAMP 4096
#define D_DIM  128
#define N_ROWS 8192
#define NCLS   64
#define NCHUNK 16
#define CCHUNK 512
#define TC     64
#define NTILE  (CCHUNK / TC)
#define THR_DOT 2.1f   // = 30 logit units; dropped terms < e^-30 relative to running max
#define NBLK   256
#define NTHR   512

// workspace offsets (bytes)
#define OFF_FB    0                                   // bf16 features [8192][128] = 2 MiB
#define OFF_PM    (OFF_FB   + N_ROWS*D_DIM*2)         // chunk max  [16][8192] f32
#define OFF_PS    (OFF_PM   + NCHUNK*N_ROWS*4)        // chunk sum  [16][8192] f32
#define OFF_CLS   (OFF_PS   + NCHUNK*N_ROWS*4)        // class id   [4096]
#define OFF_CNT4  (OFF_CLS  + B_SAMP*4)               // quarter counts [256]
#define OFF_F4    (OFF_CNT4 + 256*4)                  // quarter class sums [256][128] f32
#define OFF_G     (OFF_F4   + 256*D_DIM*4)            // G [64][128] f32
#define OFF_WMC   (OFF_G    + NCLS*D_DIM*4)
#define OFF_WC    (OFF_WMC  + 256)
#define OFF_GD    (OFF_WC   + 256)
#define OFF_MD    (OFF_GD   + 256)
#define OFF_PART  (OFF_MD   + 256)                    // per-block loss partials [256]
#define OFF_NRM   (OFF_PART + 1024)                   // fp32 row norms [8192]

typedef __attribute__((ext_vector_type(8))) short short8;
typedef __attribute__((ext_vector_type(4))) float f32x4;

__device__ __forceinline__ float inv_temp() { return 1.0f / (0.07f + 1e-8f); }

__device__ __forceinline__ void jac(int a, int b, float& mv, float& mk) {
    int u = __popc(a & b);
    int l = __popc(a | b);
    mv = (float)u / ((float)l + 1e-8f);
    mk = (mv >= 0.3f) ? 1.0f : 0.0f;
}

__device__ __forceinline__ ushort bf16rne(float x) {
    uint u = __float_as_uint(x);
    u += 0x7FFF + ((u >> 16) & 1);
    return (ushort)(u >> 16);
}

// ---------------- single fused cooperative kernel ----------------
// 256 blocks x 512 thr, 1 block/CU (128 KiB LDS). Rounds 3-7 lesson: per-kernel
// top-5 visibility was lost (all < 39us) and predicted per-kernel savings kept
// not materializing; fusing removes the 4 graph gaps and produces ONE dispatch
// whose counters are unambiguous.
__global__ __launch_bounds__(NTHR, 2) void k_fused(const float* __restrict__ feats,
                                                   const int* __restrict__ labels,
                                                   char* __restrict__ ws,
                                                   float* __restrict__ out) {
    ushort* fb    = (ushort*)(ws + OFF_FB);
    float*  pm    = (float*)(ws + OFF_PM);
    float*  ps    = (float*)(ws + OFF_PS);
    int*    cls   = (int*)(ws + OFF_CLS);
    int*    cnt4  = (int*)(ws + OFF_CNT4);
    float*  F4    = (float*)(ws + OFF_F4);
    float*  G     = (float*)(ws + OFF_G);
    float*  WmC   = (float*)(ws + OFF_WMC);
    float*  WC    = (float*)(ws + OFF_WC);
    float*  gdiag = (float*)(ws + OFF_GD);
    float*  mdiag = (float*)(ws + OFF_MD);
    float*  partial = (float*)(ws + OFF_PART);
    float*  nrm2v = (float*)(ws + OFF_NRM);

    __shared__ union Sh {
        ushort Bs[16][CCHUNK * 8];                            // 128 KiB (phase 3)
        struct { int list[1024]; float fsum[16][D_DIM]; int lcnt; } p1;  // ~12 KiB (phase 1)
        float red[16];                                        // phases 4/5
    } sh;

    const float invT = inv_temp();
    int b = blockIdx.x, t = threadIdx.x, lane = t & 63, w = t >> 6;
    cg::grid_group grid = cg::this_grid();

    // ================= phase 1: cast + norms + per-quarter class sums =================
    if (t == 0) sh.p1.lcnt = 0;
    __syncthreads();
    {
        // 1a: cast rows b*32 .. b*32+31 (16 threads/row, 8 floats each) + fp32 norm
        int n = b * 32 + (t >> 4);
        int g = t & 15;
        int samp = n & (B_SAMP - 1), view = n >> 12;
        const float* src = feats + (size_t)samp * 256 + (size_t)view * 128 + g * 8;
        float4 v0 = *(const float4*)src;
        float4 v1 = *(const float4*)(src + 4);
        short8 hv;
        hv[0] = (short)bf16rne(v0.x); hv[1] = (short)bf16rne(v0.y);
        hv[2] = (short)bf16rne(v0.z); hv[3] = (short)bf16rne(v0.w);
        hv[4] = (short)bf16rne(v1.x); hv[5] = (short)bf16rne(v1.y);
        hv[6] = (short)bf16rne(v1.z); hv[7] = (short)bf16rne(v1.w);
        *(short8*)&fb[(size_t)n * D_DIM + g * 8] = hv;
        float qs = v0.x*v0.x + v0.y*v0.y + v0.z*v0.z + v0.w*v0.w
                 + v1.x*v1.x + v1.y*v1.y + v1.z*v1.z + v1.w*v1.w;
#pragma unroll
        for (int o = 8; o; o >>= 1) qs += __shfl_xor(qs, o);
        if (g == 0) nrm2v[n] = qs;

        // 1b: class scan -- block handles class b>>2, sample quarter b&3
        int c = b >> 2, qr = b & 3;
        for (int s = qr * 1024 + t; s < qr * 1024 + 1024; s += NTHR) {
            int code = 0;
#pragma unroll
            for (int k = 0; k < 6; k++) code |= (labels[s * 6 + k] != 0) << k;
            if (code == c) {
                int idx = atomicAdd(&sh.p1.lcnt, 1);
                sh.p1.list[idx] = s;
                cls[s] = c;
            }
        }
        __syncthreads();
        int cnt = sh.p1.lcnt;
        if (t == 0) cnt4[b] = cnt;

        // 1c: F quarter-partial; half-wave (32 lanes x float4) per row
        int hw = w * 2 + (lane >> 5);
        int hl = lane & 31;
        float4 acc = make_float4(0.f, 0.f, 0.f, 0.f);
        for (int i = hw; i < 2 * cnt; i += 16) {
            int s = sh.p1.list[i >> 1];
            int v = i & 1;
            float4 fv = *(const float4*)(feats + (size_t)s * 256 + (size_t)v * 128 + hl * 4);
            acc.x += fv.x; acc.y += fv.y; acc.z += fv.z; acc.w += fv.w;
        }
        *(float4*)&sh.p1.fsum[hw][hl * 4] = acc;
        __syncthreads();
        if (t < D_DIM) {
            float sum = 0.f;
#pragma unroll
            for (int k2 = 0; k2 < 16; k2++) sum += sh.p1.fsum[k2][t];
            F4[b * D_DIM + t] = sum;
        }
    }
    grid.sync();

    // ================= phase 2: class tables =================
    if (b < NCLS) {
        if (t < D_DIM) {
            float sum = 0.f;
            for (int c2 = 0; c2 < NCLS; c2++) {
                float mv, mk; jac(b, c2, mv, mk);
                float coef = mv * mk;
                if (coef != 0.f) {
                    const float* fp = F4 + (size_t)c2 * 4 * D_DIM + t;
                    sum += coef * ((fp[0] + fp[D_DIM]) + (fp[2 * D_DIM] + fp[3 * D_DIM]));
                }
            }
            G[b * D_DIM + t] = sum;
        }
        if (t == 0) {
            float wm = 0.f, wv = 0.f;
            for (int c2 = 0; c2 < NCLS; c2++) {
                float mv, mk; jac(b, c2, mv, mk);
                float cnt2 = 2.0f * (float)(cnt4[c2 * 4] + cnt4[c2 * 4 + 1] + cnt4[c2 * 4 + 2] + cnt4[c2 * 4 + 3]);
                wm += mv * mk * cnt2;
                wv += mk * cnt2;
            }
            float mv, mk; jac(b, b, mv, mk);
            WmC[b] = wm; WC[b] = wv; gdiag[b] = mv * mk; mdiag[b] = mk;
        }
    }
    grid.sync();

    // ================= phase 3: bf16 MFMA GEMM (gemm7 body) =================
    {
        int rowBlk = b & 15;
        int chunk  = b >> 4;
        int rowbase = rowBlk * 512 + w * 64;
        int colChunk = chunk * CCHUNK;
        int r0 = (lane >> 4) * 4;

        short8 a[4][4];
        {
            int r = lane & 15, kb = (lane >> 4) * 8;
#pragma unroll
            for (int rf = 0; rf < 4; rf++)
#pragma unroll
                for (int kk = 0; kk < 4; kk++)
                    a[rf][kk] = *(const short8*)&fb[(size_t)(rowbase + rf * 16 + r) * D_DIM + kk * 32 + kb];
        }

        float m[16], s[16];
#pragma unroll
        for (int rf = 0; rf < 4; rf++)
#pragma unroll
            for (int r = 0; r < 4; r++) {
                m[rf * 4 + r] = nrm2v[rowbase + rf * 16 + r0 + r];
                s[rf * 4 + r] = 0.0f;
            }

#pragma unroll
        for (int j = 0; j < 16; j++) {
            const ushort* g = fb + (size_t)(colChunk + w * 64 + lane) * D_DIM + j * 8;
            __builtin_amdgcn_global_load_lds((const __attribute__((address_space(1))) void*)g,
                (__attribute__((address_space(3))) void*)&sh.Bs[j][w * 64 * 8], 16, 0, 0);
        }
        __syncthreads();

        short8 b0[4], b1[4];
#define LDB(dst, tt, cf)                                                        \
        {                                                                       \
            int col_ = (tt) * TC + (cf) * 16 + (lane & 15);                     \
            _Pragma("unroll")                                                   \
            for (int kk = 0; kk < 4; kk++)                                      \
                dst[kk] = *(const short8*)&sh.Bs[kk * 4 + (lane >> 4)][col_ * 8];\
        }
#define MFMA16(bb, cf)                                                          \
        {                                                                       \
            __builtin_amdgcn_s_setprio(1);                                      \
            _Pragma("unroll")                                                   \
            for (int rf = 0; rf < 4; rf++)                                      \
                _Pragma("unroll")                                               \
                for (int kk = 0; kk < 4; kk++)                                  \
                    acc[rf][cf] = __builtin_amdgcn_mfma_f32_16x16x32_bf16(      \
                        a[rf][kk], bb[kk], acc[rf][cf], 0, 0, 0);               \
            __builtin_amdgcn_s_setprio(0);                                      \
        }

        LDB(b0, 0, 0);
        for (int tt = 0; tt < NTILE; tt++) {
            f32x4 acc[4][4];
#pragma unroll
            for (int rf = 0; rf < 4; rf++)
#pragma unroll
                for (int cf = 0; cf < 4; cf++)
                    acc[rf][cf] = (f32x4){0.f, 0.f, 0.f, 0.f};

            LDB(b1, tt, 1);
            MFMA16(b0, 0);
            LDB(b0, tt, 2);
            MFMA16(b1, 1);
            LDB(b1, tt, 3);
            MFMA16(b0, 2);
            { int tn = (tt + 1 < NTILE) ? tt + 1 : 0; LDB(b0, tn, 0); }
            MFMA16(b1, 3);

            float tmax[16];
            int act = 0;
#pragma unroll
            for (int rf = 0; rf < 4; rf++)
#pragma unroll
                for (int r = 0; r < 4; r++) {
                    int idx = rf * 4 + r;
                    float t0 = fmaxf(acc[rf][0][r], acc[rf][1][r]);
                    float t1 = fmaxf(acc[rf][2][r], acc[rf][3][r]);
                    tmax[idx] = fmaxf(t0, t1);
                    act |= (tmax[idx] > m[idx] - THR_DOT) ? 1 : 0;
                }
            if (__any(act)) {
                int tileCol = colChunk + tt * TC + (lane & 15);
#pragma unroll
                for (int rf = 0; rf < 4; rf++)
#pragma unroll
                    for (int r = 0; r < 4; r++) {
                        int idx = rf * 4 + r;
                        int grow = rowbase + rf * 16 + r0 + r;
                        float nm = fmaxf(m[idx], tmax[idx]);
                        float sc = __expf((m[idx] - nm) * invT);
                        float v0 = acc[rf][0][r], v1 = acc[rf][1][r], v2 = acc[rf][2][r], v3 = acc[rf][3][r];
                        float e0 = (tileCol      == grow) ? 0.f : __expf((v0 - nm) * invT);
                        float e1 = (tileCol + 16 == grow) ? 0.f : __expf((v1 - nm) * invT);
                        float e2 = (tileCol + 32 == grow) ? 0.f : __expf((v2 - nm) * invT);
                        float e3 = (tileCol + 48 == grow) ? 0.f : __expf((v3 - nm) * invT);
                        s[idx] = s[idx] * sc + ((e0 + e1) + (e2 + e3));
                        m[idx] = nm;
                    }
            }
        }
#undef LDB
#undef MFMA16

#pragma unroll
        for (int i = 0; i < 16; i++) {
#pragma unroll
            for (int off = 1; off < 16; off <<= 1) {
                float om = __shfl_xor(m[i], off);
                float os = __shfl_xor(s[i], off);
                float nm = fmaxf(m[i], om);
                s[i] = s[i] * __expf((m[i] - nm) * invT) + os * __expf((om - nm) * invT);
                m[i] = nm;
            }
        }
        if ((lane & 15) == 0) {
#pragma unroll
            for (int rf = 0; rf < 4; rf++)
#pragma unroll
                for (int r = 0; r < 4; r++) {
                    int grow = rowbase + rf * 16 + r0 + r;
                    pm[chunk * N_ROWS + grow] = m[rf * 4 + r];
                    ps[chunk * N_ROWS + grow] = s[rf * 4 + r];
                }
        }
    }
    grid.sync();

    // ================= phase 4: chunk-merge + f.G + per-row loss =================
    {
        float lsum = 0.f;
        for (int j = 0; j < 4; j++) {
            int n = b * 32 + w * 4 + j;
            int samp = n & (B_SAMP - 1), view = n >> 12;
            int cc = cls[samp];
            const float* f = feats + (size_t)samp * 256 + (size_t)view * 128;
            const float* g = G + (size_t)cc * D_DIM;
            float2 fv = *(const float2*)(f + lane * 2);
            float2 gv = *(const float2*)(g + lane * 2);
            float dg = fv.x * gv.x + fv.y * gv.y;
#pragma unroll
            for (int o = 32; o; o >>= 1) dg += __shfl_down(dg, o);

            float m = -INFINITY, s = 0.0f;
            if (lane < 16) { m = pm[lane * N_ROWS + n]; s = ps[lane * N_ROWS + n]; }
#pragma unroll
            for (int off = 8; off; off >>= 1) {
                float om = __shfl_xor(m, off);
                float os = __shfl_xor(s, off);
                float nm = fmaxf(m, om);
                s = s * __expf((m - nm) * invT) + os * __expf((om - nm) * invT);
                m = nm;
            }
            if (lane == 0) {
                float wm = WmC[cc] - gdiag[cc];
                float wv = WC[cc] - mdiag[cc];
                float swl = (dg - gdiag[cc] * nrm2v[n]) * invT;
                float lp = swl - wm * (m * invT) - wm * logf(s + 1e-8f);
                lsum += -lp / (wv + 1e-8f);
            }
        }
        if (lane == 0) sh.red[w] = lsum;
        __syncthreads();
        if (t == 0) {
            float p = 0.f;
#pragma unroll
            for (int k = 0; k < 8; k++) p += sh.red[k];
            partial[b] = p;
        }
    }
    grid.sync();

    // ================= phase 5: final reduce (block 0) =================
    if (b == 0) {
        float s = (t < NBLK) ? partial[t] : 0.f;
#pragma unroll
        for (int o = 32; o; o >>= 1) s += __shfl_down(s, o);
        if (lane == 0) sh.red[w] = s;
        __syncthreads();
        if (t == 0)
            out[0] = (((sh.red[0] + sh.red[1]) + (sh.red[2] + sh.red[3])) +
                      ((sh.red[4] + sh.red[5]) + (sh.red[6] + sh.red[7]))) / (float)N_ROWS;
    }
}

extern "C" void kernel_launch(void* const* d_in, const int* in_sizes, int n_in,
                              void* d_out, int out_size, void* d_ws, size_t ws_size,
                              hipStream_t stream) {
    const float* feats  = (const float*)d_in[0];
    const int*   labels = (const int*)d_in[1];
    char* ws = (char*)d_ws;
    float* out = (float*)d_out;
    void* args[] = { (void*)&feats, (void*)&labels, (void*)&ws, (void*)&out };
    hipLaunchCooperativeKernel((void*)k_fused, dim3(NBLK), dim3(NTHR), args, 0, stream);
}

// Round 9
// 114.263 us; speedup vs baseline: 1.5364x; 1.5364x over previous
//
#include <hip/hip_runtime.h>
#include <cstdint>
#include <math.h>

#define B_SAMP 4096
#define D_DIM  128
#define N_ROWS 8192
#define NCLS   64
#define NCH    32          // col-chunks of 256
#define CCH    256
#define TC     64
#define NTILE2 4           // 256/64
#define THR_DOT 2.1f       // 30 logit units; dropped terms < e^-30 rel. running max
#define NBLK3  2048        // final kernel blocks

typedef __attribute__((ext_vector_type(8))) short short8;
typedef __attribute__((ext_vector_type(4))) float f32x4;

__device__ __forceinline__ float inv_temp() { return 1.0f / (0.07f + 1e-8f); }

__device__ __forceinline__ void jac(int a, int b, float& mv, float& mk) {
    int u = __popc(a & b);
    int l = __popc(a | b);
    mv = (float)u / ((float)l + 1e-8f);
    mk = (mv >= 0.3f) ? 1.0f : 0.0f;
}

__device__ __forceinline__ ushort bf16rne(float x) {
    uint u = __float_as_uint(x);
    u += 0x7FFF + ((u >> 16) & 1);
    return (ushort)(u >> 16);
}

// ---------------- K1: class-per-block cast + class sums + norms (+ticket reset) ----------------
__global__ void k_castfeat2(const float* __restrict__ feats, const int* __restrict__ labels,
                            int* __restrict__ cls, int* __restrict__ count, float* __restrict__ F,
                            ushort* __restrict__ fb, float* __restrict__ nrm2v,
                            unsigned* __restrict__ ticket) {
    __shared__ int list[B_SAMP];
    __shared__ float fsum[4][D_DIM];
    __shared__ int lcnt;
    int c = blockIdx.x, t = threadIdx.x, lane = t & 63, w = t >> 6;
    if (c == 0 && t == 0) *ticket = 0;     // reset K3's ticket every call (ws is poisoned once)
    if (t == 0) lcnt = 0;
    __syncthreads();
    for (int s = t; s < B_SAMP; s += 256) {
        int code = 0;
#pragma unroll
        for (int k = 0; k < 6; k++) code |= (labels[s * 6 + k] != 0) << k;
        if (code == c) {
            int idx = atomicAdd(&lcnt, 1);
            list[idx] = s;
            cls[s] = c;
        }
    }
    __syncthreads();
    int cnt = lcnt;
    if (t == 0) count[c] = cnt;
    float2 acc = make_float2(0.f, 0.f);
    for (int i = w; i < 2 * cnt; i += 4) {
        int s = list[i >> 1];
        int v = i & 1;
        const float* src = feats + (size_t)s * 256 + (size_t)v * 128;
        float2 fv = *(const float2*)(src + lane * 2);
        acc.x += fv.x; acc.y += fv.y;
        ushort2 h; h.x = bf16rne(fv.x); h.y = bf16rne(fv.y);
        *(ushort2*)&fb[(size_t)(v * B_SAMP + s) * D_DIM + lane * 2] = h;
        float qs = fv.x * fv.x + fv.y * fv.y;
#pragma unroll
        for (int o = 32; o; o >>= 1) qs += __shfl_xor(qs, o);
        if (lane == 0) nrm2v[v * B_SAMP + s] = qs;
    }
    fsum[w][lane * 2] = acc.x;
    fsum[w][lane * 2 + 1] = acc.y;
    __syncthreads();
    if (t < D_DIM)
        F[c * D_DIM + t] = (fsum[0][t] + fsum[1][t]) + (fsum[2][t] + fsum[3][t]);
}

// ---------------- K2: class tables G, Wm, W, diag terms ----------------
__global__ void k_tables(const float* __restrict__ F, const int* __restrict__ count,
                         float* G, float* WmC, float* WC, float* gdiag, float* mdiag) {
    int c = blockIdx.x;
    int d = threadIdx.x;
    float sum = 0.0f;
    for (int c2 = 0; c2 < NCLS; c2++) {
        float mv, mk; jac(c, c2, mv, mk);
        sum += mv * mk * F[c2 * D_DIM + d];
    }
    G[c * D_DIM + d] = sum;
    if (d == 0) {
        float wm = 0.0f, wv = 0.0f;
        for (int c2 = 0; c2 < NCLS; c2++) {
            float mv, mk; jac(c, c2, mv, mk);
            float cnt2 = 2.0f * (float)count[c2];
            wm += mv * mk * cnt2;
            wv += mk * cnt2;
        }
        float mv, mk; jac(c, c, mv, mk);
        WmC[c] = wm; WC[c] = wv; gdiag[c] = mv * mk; mdiag[c] = mk;
    }
}

// ---------------- K3: bf16 MFMA GEMM, 4 waves/SIMD ----------------
// Rounds 3-8 lesson: every 2-waves/SIMD variant pinned at 30-47us (MFMA 13-15%,
// occ 8-9%) regardless of inner-loop style -> latency-bound, not ALU/LDS-bound.
// This version: wave = 32 rows x 64-col tiles (A 32 + acc 32 + b 16 + m/s 16
// ~115 VGPR <= 128), chunk = 256 cols (64 KiB LDS) -> launch_bounds(512,4)
// gives 2 blocks/CU = 16 waves/CU = 4 waves/SIMD, doubling latency hiding.
// grid: 1024 blocks = 32 rowBlks (256 rows) x 32 chunks (256 cols).
__launch_bounds__(512, 4)
__global__ void k_gemm8(const ushort* __restrict__ fb, const float* __restrict__ nrm2v,
                        float* __restrict__ pm, float* __restrict__ ps) {
    __shared__ ushort Bs[16][CCH * 8];   // 16 k-slices x 256 cols x 8 ushort = 64 KiB
    const float invT = inv_temp();
    int tid = threadIdx.x;
    int lane = tid & 63, w = tid >> 6;
    int rowBlk = blockIdx.x & 31;
    int chunk  = blockIdx.x >> 5;
    int rowbase = rowBlk * 256 + w * 32;
    int colChunk = chunk * CCH;
    int r0 = (lane >> 4) * 4;

    // A fragments: lane holds row rowbase+rf*16+(lane&15), k = kk*32+(lane>>4)*8
    short8 a[2][4];
    {
        int r = lane & 15, kb = (lane >> 4) * 8;
#pragma unroll
        for (int rf = 0; rf < 2; rf++)
#pragma unroll
            for (int kk = 0; kk < 4; kk++)
                a[rf][kk] = *(const short8*)&fb[(size_t)(rowbase + rf * 16 + r) * D_DIM + kk * 32 + kb];
    }

    float m[8], s[8];
#pragma unroll
    for (int rf = 0; rf < 2; rf++)
#pragma unroll
        for (int r = 0; r < 4; r++) {
            m[rf * 4 + r] = nrm2v[rowbase + rf * 16 + r0 + r];
            s[rf * 4 + r] = 0.0f;
        }

    // Stage: 64 wave-units (16 slices x 4 col-groups of 64); wave w does units w*8..w*8+7.
#pragma unroll
    for (int i = 0; i < 8; i++) {
        int u = w * 8 + i;
        int j = u >> 2, g4 = u & 3;
        const ushort* g = fb + (size_t)(colChunk + g4 * 64 + lane) * D_DIM + j * 8;
        __builtin_amdgcn_global_load_lds((const __attribute__((address_space(1))) void*)g,
            (__attribute__((address_space(3))) void*)&Bs[j][g4 * 512], 16, 0, 0);
    }
    __syncthreads();   // the only barrier

    for (int t = 0; t < NTILE2; t++) {
        f32x4 acc[2][4];
#pragma unroll
        for (int rf = 0; rf < 2; rf++)
#pragma unroll
            for (int cf = 0; cf < 4; cf++)
                acc[rf][cf] = (f32x4){0.f, 0.f, 0.f, 0.f};

#pragma unroll
        for (int cf = 0; cf < 4; cf++) {
            int col = t * TC + cf * 16 + (lane & 15);
            short8 b[4];
#pragma unroll
            for (int kk = 0; kk < 4; kk++)
                b[kk] = *(const short8*)&Bs[kk * 4 + (lane >> 4)][col * 8];
            // kk-outer / rf-inner: adjacent MFMAs independent (no 4-deep acc chain)
#pragma unroll
            for (int kk = 0; kk < 4; kk++)
#pragma unroll
                for (int rf = 0; rf < 2; rf++)
                    acc[rf][cf] = __builtin_amdgcn_mfma_f32_16x16x32_bf16(a[rf][kk], b[kk], acc[rf][cf], 0, 0, 0);
        }

        // wave-uniform activity test
        float tmax[8];
        int act = 0;
#pragma unroll
        for (int rf = 0; rf < 2; rf++)
#pragma unroll
            for (int r = 0; r < 4; r++) {
                int idx = rf * 4 + r;
                float t0 = fmaxf(acc[rf][0][r], acc[rf][1][r]);
                float t1 = fmaxf(acc[rf][2][r], acc[rf][3][r]);
                tmax[idx] = fmaxf(t0, t1);
                act |= (tmax[idx] > m[idx] - THR_DOT) ? 1 : 0;
            }
        if (__any(act)) {
            int tileCol = colChunk + t * TC + (lane & 15);
#pragma unroll
            for (int rf = 0; rf < 2; rf++)
#pragma unroll
                for (int r = 0; r < 4; r++) {
                    int idx = rf * 4 + r;
                    int grow = rowbase + rf * 16 + r0 + r;
                    float nm = fmaxf(m[idx], tmax[idx]);
                    float sc = __expf((m[idx] - nm) * invT);
                    float v0 = acc[rf][0][r], v1 = acc[rf][1][r], v2 = acc[rf][2][r], v3 = acc[rf][3][r];
                    float e0 = (tileCol      == grow) ? 0.f : __expf((v0 - nm) * invT);
                    float e1 = (tileCol + 16 == grow) ? 0.f : __expf((v1 - nm) * invT);
                    float e2 = (tileCol + 32 == grow) ? 0.f : __expf((v2 - nm) * invT);
                    float e3 = (tileCol + 48 == grow) ? 0.f : __expf((v3 - nm) * invT);
                    s[idx] = s[idx] * sc + ((e0 + e1) + (e2 + e3));
                    m[idx] = nm;
                }
        }
    }

    // merge the 16 col-slot partials (xor over low 4 lane bits)
#pragma unroll
    for (int i = 0; i < 8; i++) {
#pragma unroll
        for (int off = 1; off < 16; off <<= 1) {
            float om = __shfl_xor(m[i], off);
            float os = __shfl_xor(s[i], off);
            float nm = fmaxf(m[i], om);
            s[i] = s[i] * __expf((m[i] - nm) * invT) + os * __expf((om - nm) * invT);
            m[i] = nm;
        }
    }
    if ((lane & 15) == 0) {
#pragma unroll
        for (int rf = 0; rf < 2; rf++)
#pragma unroll
            for (int r = 0; r < 4; r++) {
                int grow = rowbase + rf * 16 + r0 + r;
                pm[chunk * N_ROWS + grow] = m[rf * 4 + r];
                ps[chunk * N_ROWS + grow] = s[rf * 4 + r];
            }
    }
}

// ---------------- K4: chunk-merge + f.G + per-row loss + ticketed final reduce ----------------
// grid 2048 x 256 (one wave per row); the LAST block (device ticket) sums the
// 2048 partials in fixed order and writes out -- removes the k_out dispatch.
__global__ void k_final3(const float* __restrict__ feats, const int* __restrict__ cls,
                         const float* __restrict__ G, const float* __restrict__ pm,
                         const float* __restrict__ ps, const float* __restrict__ WmC,
                         const float* __restrict__ WC, const float* __restrict__ gdiag,
                         const float* __restrict__ mdiag, const float* __restrict__ nrm2v,
                         float* __restrict__ partial, unsigned* __restrict__ ticket,
                         float* __restrict__ out) {
    const float invT = inv_temp();
    __shared__ float red[4];
    __shared__ int isLast;
    int tid = threadIdx.x;
    int lane = tid & 63, w = tid >> 6;
    int n = blockIdx.x * 4 + w;
    int samp = n & (B_SAMP - 1), view = n >> 12;
    int c = cls[samp];
    const float* f = feats + (size_t)samp * 256 + (size_t)view * 128;
    const float* g = G + (size_t)c * D_DIM;
    float2 fv = *(const float2*)(f + lane * 2);
    float2 gv = *(const float2*)(g + lane * 2);
    float dg = fv.x * gv.x + fv.y * gv.y;
#pragma unroll
    for (int o = 32; o; o >>= 1) dg += __shfl_down(dg, o);

    float m = -INFINITY, s = 0.0f;
    if (lane < 32) { m = pm[lane * N_ROWS + n]; s = ps[lane * N_ROWS + n]; }
#pragma unroll
    for (int off = 16; off; off >>= 1) {
        float om = __shfl_xor(m, off);
        float os = __shfl_xor(s, off);
        float nm = fmaxf(m, om);
        s = s * __expf((m - nm) * invT) + os * __expf((om - nm) * invT);
        m = nm;
    }
    if (lane == 0) {
        float wm = WmC[c] - gdiag[c];
        float wv = WC[c] - mdiag[c];
        float swl = (dg - gdiag[c] * nrm2v[n]) * invT;
        float lp = swl - wm * (m * invT) - wm * logf(s + 1e-8f);
        red[w] = -lp / (wv + 1e-8f);
    }
    __syncthreads();
    if (tid == 0) {
        partial[blockIdx.x] = (red[0] + red[1]) + (red[2] + red[3]);
        __threadfence();
        unsigned old = atomicAdd(ticket, 1u);
        isLast = (old == NBLK3 - 1);
    }
    __syncthreads();
    if (isLast) {
        __threadfence();
        float sum = 0.f;
        for (int i = tid; i < NBLK3; i += 256) sum += partial[i];
#pragma unroll
        for (int o = 32; o; o >>= 1) sum += __shfl_down(sum, o);
        if (lane == 0) red[w] = sum;
        __syncthreads();
        if (tid == 0) out[0] = ((red[0] + red[1]) + (red[2] + red[3])) / (float)N_ROWS;
    }
}

extern "C" void kernel_launch(void* const* d_in, const int* in_sizes, int n_in,
                              void* d_out, int out_size, void* d_ws, size_t ws_size,
                              hipStream_t stream) {
    const float* feats  = (const float*)d_in[0];
    const int*   labels = (const int*)d_in[1];
    float* out = (float*)d_out;

    char* ws = (char*)d_ws;
    ushort* fb    = (ushort*)ws;              ws += (size_t)N_ROWS * D_DIM * 2;   // 2 MiB
    float* pm     = (float*)ws;               ws += (size_t)NCH * N_ROWS * 4;     // 1 MiB
    float* ps     = (float*)ws;               ws += (size_t)NCH * N_ROWS * 4;     // 1 MiB
    int*   cls    = (int*)ws;                 ws += B_SAMP * 4;
    int*   count  = (int*)ws;                 ws += NCLS * 4;
    float* F      = (float*)ws;               ws += NCLS * D_DIM * 4;
    float* G      = (float*)ws;               ws += NCLS * D_DIM * 4;
    float* WmC    = (float*)ws;               ws += NCLS * 4;
    float* WC     = (float*)ws;               ws += NCLS * 4;
    float* gdiag  = (float*)ws;               ws += NCLS * 4;
    float* mdiag  = (float*)ws;               ws += NCLS * 4;
    float* nrm2v  = (float*)ws;               ws += N_ROWS * 4;
    float* partial= (float*)ws;               ws += NBLK3 * 4;
    unsigned* ticket = (unsigned*)ws;         ws += 64;

    k_castfeat2<<<NCLS, 256, 0, stream>>>(feats, labels, cls, count, F, fb, nrm2v, ticket);
    k_tables   <<<NCLS, 128, 0, stream>>>(F, count, G, WmC, WC, gdiag, mdiag);
    k_gemm8    <<<1024, 512, 0, stream>>>(fb, nrm2v, pm, ps);
    k_final3   <<<NBLK3, 256, 0, stream>>>(feats, cls, G, pm, ps, WmC, WC, gdiag, mdiag,
                                           nrm2v, partial, ticket, out);
}

// Round 10
// 74.943 us; speedup vs baseline: 2.3425x; 1.5247x over previous
//
#include <hip/hip_runtime.h>
#include <cstdint>
#include <math.h>

#define B_SAMP 4096
#define D_DIM  128
#define N_ROWS 8192
#define NCLS   64
#define NCH    32          // col-chunks of 256
#define CCH    256
#define TC     64
#define NTILE2 4           // 256/64
#define THR_DOT 2.1f       // 30 logit units; dropped terms < e^-30 rel. running max

typedef __attribute__((ext_vector_type(8))) short short8;
typedef __attribute__((ext_vector_type(4))) float f32x4;

__device__ __forceinline__ float inv_temp() { return 1.0f / (0.07f + 1e-8f); }

__device__ __forceinline__ void jac(int a, int b, float& mv, float& mk) {
    int u = __popc(a & b);
    int l = __popc(a | b);
    mv = (float)u / ((float)l + 1e-8f);
    mk = (mv >= 0.3f) ? 1.0f : 0.0f;
}

__device__ __forceinline__ ushort bf16rne(float x) {
    uint u = __float_as_uint(x);
    u += 0x7FFF + ((u >> 16) & 1);
    return (ushort)(u >> 16);
}

// ---------------- K1: class-per-block cast + class sums + norms ----------------
__global__ void k_castfeat2(const float* __restrict__ feats, const int* __restrict__ labels,
                            int* __restrict__ cls, int* __restrict__ count, float* __restrict__ F,
                            ushort* __restrict__ fb, float* __restrict__ nrm2v) {
    __shared__ int list[B_SAMP];
    __shared__ float fsum[4][D_DIM];
    __shared__ int lcnt;
    int c = blockIdx.x, t = threadIdx.x, lane = t & 63, w = t >> 6;
    if (t == 0) lcnt = 0;
    __syncthreads();
    for (int s = t; s < B_SAMP; s += 256) {
        int code = 0;
#pragma unroll
        for (int k = 0; k < 6; k++) code |= (labels[s * 6 + k] != 0) << k;
        if (code == c) {
            int idx = atomicAdd(&lcnt, 1);
            list[idx] = s;
            cls[s] = c;
        }
    }
    __syncthreads();
    int cnt = lcnt;
    if (t == 0) count[c] = cnt;
    float2 acc = make_float2(0.f, 0.f);
    for (int i = w; i < 2 * cnt; i += 4) {
        int s = list[i >> 1];
        int v = i & 1;
        const float* src = feats + (size_t)s * 256 + (size_t)v * 128;
        float2 fv = *(const float2*)(src + lane * 2);
        acc.x += fv.x; acc.y += fv.y;
        ushort2 h; h.x = bf16rne(fv.x); h.y = bf16rne(fv.y);
        *(ushort2*)&fb[(size_t)(v * B_SAMP + s) * D_DIM + lane * 2] = h;
        float qs = fv.x * fv.x + fv.y * fv.y;
#pragma unroll
        for (int o = 32; o; o >>= 1) qs += __shfl_xor(qs, o);
        if (lane == 0) nrm2v[v * B_SAMP + s] = qs;
    }
    fsum[w][lane * 2] = acc.x;
    fsum[w][lane * 2 + 1] = acc.y;
    __syncthreads();
    if (t < D_DIM)
        F[c * D_DIM + t] = (fsum[0][t] + fsum[1][t]) + (fsum[2][t] + fsum[3][t]);
}

// ---------------- K2: class tables G, Wm, W, diag terms ----------------
__global__ void k_tables(const float* __restrict__ F, const int* __restrict__ count,
                         float* G, float* WmC, float* WC, float* gdiag, float* mdiag) {
    int c = blockIdx.x;
    int d = threadIdx.x;
    float sum = 0.0f;
    for (int c2 = 0; c2 < NCLS; c2++) {
        float mv, mk; jac(c, c2, mv, mk);
        sum += mv * mk * F[c2 * D_DIM + d];
    }
    G[c * D_DIM + d] = sum;
    if (d == 0) {
        float wm = 0.0f, wv = 0.0f;
        for (int c2 = 0; c2 < NCLS; c2++) {
            float mv, mk; jac(c, c2, mv, mk);
            float cnt2 = 2.0f * (float)count[c2];
            wm += mv * mk * cnt2;
            wv += mk * cnt2;
        }
        float mv, mk; jac(c, c, mv, mk);
        WmC[c] = wm; WC[c] = wv; gdiag[c] = mv * mk; mdiag[c] = mk;
    }
}

// ---------------- K3: bf16 MFMA GEMM, 4 waves/SIMD; pm/ps row-major writes ----------------
// Round-9 lesson: k_final3's 48us came from per-block __threadfence (cross-XCD L2
// writeback) + stride-32KB pm/ps gathers, NOT from the gemm. pm/ps now [n][32]
// so the final kernel reads one coalesced 128B line per wave.
__launch_bounds__(512, 4)
__global__ void k_gemm8(const ushort* __restrict__ fb, const float* __restrict__ nrm2v,
                        float* __restrict__ pm, float* __restrict__ ps) {
    __shared__ ushort Bs[16][CCH * 8];   // 16 k-slices x 256 cols x 8 ushort = 64 KiB
    const float invT = inv_temp();
    int tid = threadIdx.x;
    int lane = tid & 63, w = tid >> 6;
    int rowBlk = blockIdx.x & 31;
    int chunk  = blockIdx.x >> 5;
    int rowbase = rowBlk * 256 + w * 32;
    int colChunk = chunk * CCH;
    int r0 = (lane >> 4) * 4;

    short8 a[2][4];
    {
        int r = lane & 15, kb = (lane >> 4) * 8;
#pragma unroll
        for (int rf = 0; rf < 2; rf++)
#pragma unroll
            for (int kk = 0; kk < 4; kk++)
                a[rf][kk] = *(const short8*)&fb[(size_t)(rowbase + rf * 16 + r) * D_DIM + kk * 32 + kb];
    }

    float m[8], s[8];
#pragma unroll
    for (int rf = 0; rf < 2; rf++)
#pragma unroll
        for (int r = 0; r < 4; r++) {
            m[rf * 4 + r] = nrm2v[rowbase + rf * 16 + r0 + r];
            s[rf * 4 + r] = 0.0f;
        }

    // Stage: 64 wave-units (16 slices x 4 col-groups of 64); wave w does units w*8..w*8+7.
#pragma unroll
    for (int i = 0; i < 8; i++) {
        int u = w * 8 + i;
        int j = u >> 2, g4 = u & 3;
        const ushort* g = fb + (size_t)(colChunk + g4 * 64 + lane) * D_DIM + j * 8;
        __builtin_amdgcn_global_load_lds((const __attribute__((address_space(1))) void*)g,
            (__attribute__((address_space(3))) void*)&Bs[j][g4 * 512], 16, 0, 0);
    }
    __syncthreads();   // the only barrier

    for (int t = 0; t < NTILE2; t++) {
        f32x4 acc[2][4];
#pragma unroll
        for (int rf = 0; rf < 2; rf++)
#pragma unroll
            for (int cf = 0; cf < 4; cf++)
                acc[rf][cf] = (f32x4){0.f, 0.f, 0.f, 0.f};

#pragma unroll
        for (int cf = 0; cf < 4; cf++) {
            int col = t * TC + cf * 16 + (lane & 15);
            short8 b[4];
#pragma unroll
            for (int kk = 0; kk < 4; kk++)
                b[kk] = *(const short8*)&Bs[kk * 4 + (lane >> 4)][col * 8];
#pragma unroll
            for (int kk = 0; kk < 4; kk++)
#pragma unroll
                for (int rf = 0; rf < 2; rf++)
                    acc[rf][cf] = __builtin_amdgcn_mfma_f32_16x16x32_bf16(a[rf][kk], b[kk], acc[rf][cf], 0, 0, 0);
        }

        float tmax[8];
        int act = 0;
#pragma unroll
        for (int rf = 0; rf < 2; rf++)
#pragma unroll
            for (int r = 0; r < 4; r++) {
                int idx = rf * 4 + r;
                float t0 = fmaxf(acc[rf][0][r], acc[rf][1][r]);
                float t1 = fmaxf(acc[rf][2][r], acc[rf][3][r]);
                tmax[idx] = fmaxf(t0, t1);
                act |= (tmax[idx] > m[idx] - THR_DOT) ? 1 : 0;
            }
        if (__any(act)) {
            int tileCol = colChunk + t * TC + (lane & 15);
#pragma unroll
            for (int rf = 0; rf < 2; rf++)
#pragma unroll
                for (int r = 0; r < 4; r++) {
                    int idx = rf * 4 + r;
                    int grow = rowbase + rf * 16 + r0 + r;
                    float nm = fmaxf(m[idx], tmax[idx]);
                    float sc = __expf((m[idx] - nm) * invT);
                    float v0 = acc[rf][0][r], v1 = acc[rf][1][r], v2 = acc[rf][2][r], v3 = acc[rf][3][r];
                    float e0 = (tileCol      == grow) ? 0.f : __expf((v0 - nm) * invT);
                    float e1 = (tileCol + 16 == grow) ? 0.f : __expf((v1 - nm) * invT);
                    float e2 = (tileCol + 32 == grow) ? 0.f : __expf((v2 - nm) * invT);
                    float e3 = (tileCol + 48 == grow) ? 0.f : __expf((v3 - nm) * invT);
                    s[idx] = s[idx] * sc + ((e0 + e1) + (e2 + e3));
                    m[idx] = nm;
                }
        }
    }

#pragma unroll
    for (int i = 0; i < 8; i++) {
#pragma unroll
        for (int off = 1; off < 16; off <<= 1) {
            float om = __shfl_xor(m[i], off);
            float os = __shfl_xor(s[i], off);
            float nm = fmaxf(m[i], om);
            s[i] = s[i] * __expf((m[i] - nm) * invT) + os * __expf((om - nm) * invT);
            m[i] = nm;
        }
    }
    if ((lane & 15) == 0) {
#pragma unroll
        for (int rf = 0; rf < 2; rf++)
#pragma unroll
            for (int r = 0; r < 4; r++) {
                int grow = rowbase + rf * 16 + r0 + r;
                pm[(size_t)grow * NCH + chunk] = m[rf * 4 + r];   // row-major [n][32]
                ps[(size_t)grow * NCH + chunk] = s[rf * 4 + r];
            }
    }
}

// ---------------- K4: chunk-merge + f.G + per-row loss (coalesced pm/ps) ----------------
// grid 2048 x 256: one wave per row; lane ch<32 reads pm[n*32+ch] -> one 128B line.
__global__ void k_final4(const float* __restrict__ feats, const int* __restrict__ cls,
                         const float* __restrict__ G, const float* __restrict__ pm,
                         const float* __restrict__ ps, const float* __restrict__ WmC,
                         const float* __restrict__ WC, const float* __restrict__ gdiag,
                         const float* __restrict__ mdiag, const float* __restrict__ nrm2v,
                         float* __restrict__ partial) {
    const float invT = inv_temp();
    __shared__ float red[4];
    int tid = threadIdx.x;
    int lane = tid & 63, w = tid >> 6;
    int n = blockIdx.x * 4 + w;
    int samp = n & (B_SAMP - 1), view = n >> 12;
    int c = cls[samp];
    const float* f = feats + (size_t)samp * 256 + (size_t)view * 128;
    const float* g = G + (size_t)c * D_DIM;
    float2 fv = *(const float2*)(f + lane * 2);
    float2 gv = *(const float2*)(g + lane * 2);
    float dg = fv.x * gv.x + fv.y * gv.y;
#pragma unroll
    for (int o = 32; o; o >>= 1) dg += __shfl_down(dg, o);

    float m = -INFINITY, s = 0.0f;
    if (lane < NCH) { m = pm[(size_t)n * NCH + lane]; s = ps[(size_t)n * NCH + lane]; }
#pragma unroll
    for (int off = 16; off; off >>= 1) {
        float om = __shfl_xor(m, off);
        float os = __shfl_xor(s, off);
        float nm = fmaxf(m, om);
        s = s * __expf((m - nm) * invT) + os * __expf((om - nm) * invT);
        m = nm;
    }
    if (lane == 0) {
        float wm = WmC[c] - gdiag[c];
        float wv = WC[c] - mdiag[c];
        float swl = (dg - gdiag[c] * nrm2v[n]) * invT;
        float lp = swl - wm * (m * invT) - wm * logf(s + 1e-8f);
        red[w] = -lp / (wv + 1e-8f);
    }
    __syncthreads();
    if (tid == 0) partial[blockIdx.x] = (red[0] + red[1]) + (red[2] + red[3]);
}

// ---------------- K5: final deterministic reduce ----------------
__global__ void k_out(const float* __restrict__ partial, float* out) {
    __shared__ float red[4];
    int t = threadIdx.x;
    float s = 0.0f;
    for (int i = t; i < 2048; i += 256) s += partial[i];
#pragma unroll
    for (int o = 32; o; o >>= 1) s += __shfl_down(s, o);
    if ((t & 63) == 0) red[t >> 6] = s;
    __syncthreads();
    if (t == 0) out[0] = ((red[0] + red[1]) + (red[2] + red[3])) / (float)N_ROWS;
}

extern "C" void kernel_launch(void* const* d_in, const int* in_sizes, int n_in,
                              void* d_out, int out_size, void* d_ws, size_t ws_size,
                              hipStream_t stream) {
    const float* feats  = (const float*)d_in[0];
    const int*   labels = (const int*)d_in[1];
    float* out = (float*)d_out;

    char* ws = (char*)d_ws;
    ushort* fb    = (ushort*)ws;              ws += (size_t)N_ROWS * D_DIM * 2;   // 2 MiB
    float* pm     = (float*)ws;               ws += (size_t)N_ROWS * NCH * 4;     // 1 MiB
    float* ps     = (float*)ws;               ws += (size_t)N_ROWS * NCH * 4;     // 1 MiB
    int*   cls    = (int*)ws;                 ws += B_SAMP * 4;
    int*   count  = (int*)ws;                 ws += NCLS * 4;
    float* F      = (float*)ws;               ws += NCLS * D_DIM * 4;
    float* G      = (float*)ws;               ws += NCLS * D_DIM * 4;
    float* WmC    = (float*)ws;               ws += NCLS * 4;
    float* WC     = (float*)ws;               ws += NCLS * 4;
    float* gdiag  = (float*)ws;               ws += NCLS * 4;
    float* mdiag  = (float*)ws;               ws += NCLS * 4;
    float* nrm2v  = (float*)ws;               ws += N_ROWS * 4;
    float* partial= (float*)ws;               ws += 2048 * 4;

    k_castfeat2<<<NCLS, 256, 0, stream>>>(feats, labels, cls, count, F, fb, nrm2v);
    k_tables   <<<NCLS, 128, 0, stream>>>(F, count, G, WmC, WC, gdiag, mdiag);
    k_gemm8    <<<1024, 512, 0, stream>>>(fb, nrm2v, pm, ps);
    k_final4   <<<2048, 256, 0, stream>>>(feats, cls, G, pm, ps, WmC, WC, gdiag, mdiag, nrm2v, partial);
    k_out      <<<1, 256, 0, stream>>>(partial, out);
}